// Round 15
// baseline (212.598 us; speedup 1.0000x reference)
//
#include <hip/hip_runtime.h>
#include <hip/hip_fp16.h>

#define NN 8192
#define DD 128

typedef _Float16 f16x8 __attribute__((ext_vector_type(8)));
typedef float f32x4 __attribute__((ext_vector_type(4)));

// ---------------------------------------------------------------------------
// prep: Xc[row][0..127] = f16(x), Xc[row][128..255] = f16(x - f16(x)).
// sim = Xc @ Xc^T equals x@x^T up to ~1e-6.
// ---------------------------------------------------------------------------
__global__ __launch_bounds__(256) void prep_kernel(const float* __restrict__ X,
                                                   _Float16* __restrict__ Xc) {
  const int t = blockIdx.x * 256 + threadIdx.x;  // 8 elems per thread
  const size_t base = (size_t)t * 8;
  const int row = (int)(base >> 7);
  const int col = (int)(base & 127);
  float4 a = *(const float4*)&X[base];
  float4 b = *(const float4*)&X[base + 4];
  const float av[8] = {a.x, a.y, a.z, a.w, b.x, b.y, b.z, b.w};
  f16x8 h, l;
#pragma unroll
  for (int e = 0; e < 8; ++e) {
    const _Float16 hh = (_Float16)av[e];
    h[e] = hh;
    l[e] = (_Float16)(av[e] - (float)hh);
  }
  *(f16x8*)&Xc[(size_t)row * 256 + col] = h;
  *(f16x8*)&Xc[(size_t)row * 256 + 128 + col] = l;
}

// ---------------------------------------------------------------------------
// sim = Xc @ Xc^T  (R12 geometry — best measured; no spill).
// 256x128 tile, 512 thr (8 waves 4x2), wave tile 64x64 (acc[4][4] fits the
// 128-VGPR cap at 4 waves/EU). BK=32, 8 K-steps, double-buffered 24KB
// (A 16KB + B 8KB) = 48 KB LDS -> 2 blocks/CU.
// HALF-SPLIT PIPELINE (R15): kernel takes ti_base (row-tile offset, units of
// 256 rows) and covers 4096 rows per launch; each 128 MiB sim half fits L3
// and is consumed by the matching row_kernel half before eviction.
// SYMMETRY ABANDONED (R2, R13). DETERMINISM RULE (R9): plain __syncthreads().
// Schedule: STAGE(0); sync; { STAGE(ks+1); compute(ks); sync; }
// Swizzle: chunk ^= row&3 on BOTH global source (inverse) and ds_read.
// A/B fragments share the identical k-mapping -> k-permutation cancels.
// C/D layout (m89): col=lane&15, row=(lane>>4)*4+reg.
// Epilogue: Tr 64x132 f32 (33.8 KB union), 4 phases, coalesced float4 stores.
// Regular (non-NT) stores on purpose: sim must be L3-resident for row_kernel.
// ---------------------------------------------------------------------------
__global__ __launch_bounds__(512, 4) void sim_mfma_kernel(
    const _Float16* __restrict__ Xc, float* __restrict__ simOut, int ti_base) {
  __shared__ char smem[49152];  // buf b @ b*24576 (A 16KB, B 8KB); Tr unions

  // bijective XCD swizzle (1024 % 8 == 0)
  const int flat = blockIdx.x;
  const int swz = (flat & 7) * 128 + (flat >> 3);
  const int i0 = ((swz >> 6) + ti_base) << 8;  // tile row (16 local tiles)
  const int j0 = (swz & 63) << 7;              // tile col (64 tiles of 128)

  const int tid = threadIdx.x;
  const int lane = tid & 63;
  const int w = tid >> 6;
  const int m = lane & 15, kq = lane >> 4;
  const int wr = w >> 1, wc = w & 1;  // wave rows wr*64+.., cols wc*64+..

  // Staging coords: 3 chunks of 16B per thread per K-step (A 16KB + B 8KB).
  int sg_off[3], sd_off[3], sg_row[3];
#pragma unroll
  for (int it = 0; it < 3; ++it) {
    const int C = it * 512 + tid;
    const int rq = C >> 2;          // row-quad index
    const int k4 = C & 3;
    const int k4p = k4 ^ (rq & 3);  // inverse swizzle on global source
    sg_row[it] = (C < 1024) ? (i0 + rq) : (j0 + rq - 256);
    sg_off[it] = k4p << 4;
    sd_off[it] = C * 16;
  }

#define STAGE(ks, b)                                                         \
  {                                                                          \
    _Pragma("unroll") for (int it = 0; it < 3; ++it) {                       \
      const char* g = (const char*)Xc + ((size_t)sg_row[it] << 9) +          \
                      (ks)*64 + sg_off[it];                                  \
      __builtin_amdgcn_global_load_lds(                                      \
          (const __attribute__((address_space(1))) void*)g,                  \
          (__attribute__((address_space(3))) void*)(smem + (b)*24576 +       \
                                                    sd_off[it]),             \
          16, 0, 0);                                                         \
    }                                                                        \
  }

  f32x4 acc[4][4] = {};

  STAGE(0, 0);
  __syncthreads();  // stage(0) landed (vmcnt 0 + barrier)

#pragma unroll
  for (int ks = 0; ks < 8; ++ks) {
    const int b = ks & 1;
    if (ks < 7) STAGE(ks + 1, b ^ 1);  // prefetch; drained at step-end sync
    const _Float16* As = (const _Float16*)(smem + b * 24576);
    const _Float16* Bs = (const _Float16*)(smem + b * 24576 + 16384);
    f16x8 af[4], bf[4];
#pragma unroll
    for (int f = 0; f < 4; ++f) {
      const int R = wr * 64 + f * 16 + m;  // R&3 == m&3
      af[f] = *(const f16x8*)(As + R * 32 + ((kq ^ (R & 3)) << 3));
    }
#pragma unroll
    for (int g = 0; g < 4; ++g) {
      const int R = wc * 64 + g * 16 + m;
      bf[g] = *(const f16x8*)(Bs + R * 32 + ((kq ^ (R & 3)) << 3));
    }
#pragma unroll
    for (int f = 0; f < 4; ++f)
#pragma unroll
      for (int g = 0; g < 4; ++g)
        acc[f][g] = __builtin_amdgcn_mfma_f32_16x16x32_f16(af[f], bf[g],
                                                           acc[f][g], 0, 0, 0);
    __syncthreads();  // drains vmcnt+lgkm; next-step buffer ready, WAR safe
  }
#undef STAGE

  // Epilogue: 4 phases of 64 rows through LDS; Tr = 64 x 132 f32 = 33.8 KB.
  float* Tr = (float*)smem;
#pragma unroll
  for (int ph = 0; ph < 4; ++ph) {
    if (ph) __syncthreads();
    if (wr == ph) {  // 2 waves (wc=0,1) own this 64-row band
#pragma unroll
      for (int f = 0; f < 4; ++f)
#pragma unroll
        for (int g = 0; g < 4; ++g)
#pragma unroll
          for (int rg = 0; rg < 4; ++rg)
            Tr[(f * 16 + kq * 4 + rg) * 132 + wc * 64 + g * 16 + m] =
                acc[f][g][rg];
    }
    __syncthreads();
#pragma unroll
    for (int it = 0; it < 4; ++it) {
      const int F = it * 512 + tid;
      const int row = F >> 5;
      const int c4 = (F & 31) * 4;
      const float4 v = *(const float4*)&Tr[row * 132 + c4];
      *(float4*)&simOut[(size_t)(i0 + ph * 64 + row) * NN + j0 + c4] = v;
    }
  }
}

// ---------------------------------------------------------------------------
// row_kernel: one block per row (i = row_base + blockIdx.x); 32 sim values
// per thread in registers, native transcendentals, branchless epilogue,
// non-temporal output stores. Launched per-half right after its sim half so
// the sim read is L3-hot.
// ---------------------------------------------------------------------------
__global__ __launch_bounds__(256) void row_kernel(const float* simG,
                                                  const int* __restrict__ tgt,
                                                  float* lossG,
                                                  float* gradG,
                                                  int row_base) {
  __shared__ unsigned char tg[NN];
  __shared__ float redA[4];
  __shared__ float redB[4];
  const int i = row_base + blockIdx.x;
  const int tid = threadIdx.x;
  const size_t rowOff = (size_t)i * NN;

  for (int b = tid * 4; b < NN; b += 1024) {
    int4 t4 = *(const int4*)&tgt[b];
    tg[b + 0] = (unsigned char)t4.x;
    tg[b + 1] = (unsigned char)t4.y;
    tg[b + 2] = (unsigned char)t4.z;
    tg[b + 3] = (unsigned char)t4.w;
  }
  const unsigned char tci = (unsigned char)tgt[i];

  float4 sv[8];
#pragma unroll
  for (int q = 0; q < 8; ++q)
    sv[q] = *(const float4*)&simG[rowOff + (size_t)(tid * 4 + q * 1024)];
  __syncthreads();

  unsigned mmask = 0;
  float lmin = 1e30f, lmax = -1e30f;
#pragma unroll
  for (int q = 0; q < 8; ++q) {
    uchar4 t4 = *(const uchar4*)&tg[tid * 4 + q * 1024];
    const unsigned char tt[4] = {t4.x, t4.y, t4.z, t4.w};
    const float* sp = (const float*)&sv[q];
#pragma unroll
    for (int e = 0; e < 4; ++e) {
      const bool same = (tt[e] == tci);
      const float s = sp[e];
      if (same) {
        mmask |= (1u << (q * 4 + e));
        if (s < 1.0f) lmin = fminf(lmin, s);
      } else {
        lmax = fmaxf(lmax, s);
      }
    }
  }
#pragma unroll
  for (int off = 32; off > 0; off >>= 1) {
    lmin = fminf(lmin, __shfl_down(lmin, off));
    lmax = fmaxf(lmax, __shfl_down(lmax, off));
  }
  if ((tid & 63) == 0) {
    redA[tid >> 6] = lmin;
    redB[tid >> 6] = lmax;
  }
  __syncthreads();
  const float minpos = fminf(fminf(redA[0], redA[1]), fminf(redA[2], redA[3]));
  const float maxneg = fmaxf(fmaxf(redB[0], redB[1]), fmaxf(redB[2], redB[3]));
  __syncthreads();

  float pc = 0.f, nc = 0.f;
#pragma unroll
  for (int q = 0; q < 8; ++q) {
    const float* sp = (const float*)&sv[q];
#pragma unroll
    for (int e = 0; e < 4; ++e) {
      const bool same = (mmask >> (q * 4 + e)) & 1u;
      const float s = sp[e];
      if (same) {
        if (s < 1.0f && (s - 0.1f) < maxneg) pc += 1.f;
      } else {
        if ((s + 0.1f) > minpos) nc += 1.f;
      }
    }
  }
#pragma unroll
  for (int off = 32; off > 0; off >>= 1) {
    pc += __shfl_down(pc, off);
    nc += __shfl_down(nc, off);
  }
  if ((tid & 63) == 0) {
    redA[tid >> 6] = pc;
    redB[tid >> 6] = nc;
  }
  __syncthreads();
  const float pcnt = redA[0] + redA[1] + redA[2] + redA[3];
  const float ncnt = redB[0] + redB[1] + redB[2] + redB[3];
  const bool valid = (pcnt >= 1.f) && (ncnt >= 1.f);
  const float cp = -2.f / fmaxf(pcnt, 1.f);
  const float cn = 2.f / fmaxf(ncnt, 1.f);

#pragma unroll
  for (int q = 0; q < 8; ++q) {
    const float* sp = (const float*)&sv[q];
    float lo[4], go[4];
#pragma unroll
    for (int e = 0; e < 4; ++e) {
      const float s = sp[e];
      const bool same = (mmask >> (q * 4 + e)) & 1u;
      bool keep = same ? (s < 1.0f && (s - 0.1f) < maxneg)
                       : ((s + 0.1f) > minpos);
      keep = keep && valid;
      const float z = same ? fmaf(-2.f, s, 1.f) : fmaf(40.f, s, -20.f);
      const float ez = __expf(z);
      const float d = 1.f + ez;
      const float ll = __logf(d);
      const float sig = __fdividef(ez, d);
      const float lv = same ? ll : 0.05f * ll;
      const float gv = (same ? cp : cn) * sig;
      lo[e] = keep ? lv : 0.f;
      go[e] = keep ? gv : 0.f;
    }
    const size_t a = rowOff + (size_t)(tid * 4 + q * 1024);
    f32x4 lv4 = {lo[0], lo[1], lo[2], lo[3]};
    f32x4 gv4 = {go[0], go[1], go[2], go[3]};
    __builtin_nontemporal_store(lv4, (f32x4*)&lossG[a]);
    __builtin_nontemporal_store(gv4, (f32x4*)&gradG[a]);
  }
}

extern "C" void kernel_launch(void* const* d_in, const int* in_sizes, int n_in,
                              void* d_out, int out_size, void* d_ws,
                              size_t ws_size, hipStream_t stream) {
  const float* X = (const float*)d_in[0];
  const int* tgt = (const int*)d_in[1];
  float* out = (float*)d_out;
  float* lossG = out;                    // first N*N: pair_loss
  float* gradG = out + (size_t)NN * NN;  // second N*N: pair_grad (sim scratch)

  // Xc (4 MiB f16) lives in the loss half of d_out: only read by sim_mfma,
  // and row_kernel half-launches overwrite lossG rows strictly after the
  // corresponding sim rows are materialized; Xc occupies loss rows 0..127,
  // whose row_kernel blocks run in the FIRST row half — but Xc is still
  // needed by the SECOND sim half. So place Xc at the END of lossG instead:
  // loss rows 8064..8191 are only written by the LAST row half... also needed
  // until then. Use gradG tail instead: gradG rows 8064..8191 are written by
  // sim half 2 (tiles covering rows 4096..8191) — also a conflict.
  // Resolution: Xc in the tail of LOSS half, and order launches so the final
  // row half (which overwrites loss rows 8064..8191) runs LAST, after every
  // reader of Xc (prep once, sim half 1, sim half 2) has completed.
  _Float16* Xc = (_Float16*)(lossG + (size_t)(NN - 128) * NN);  // last 4 MiB

  hipLaunchKernelGGL(prep_kernel, dim3(NN * DD / (256 * 8)), dim3(256), 0,
                     stream, X, Xc);
  // half 1: sim rows 0..4095, then row 0..4095 (sim half L3-hot)
  hipLaunchKernelGGL(sim_mfma_kernel, dim3(16 * 64), dim3(512), 0, stream, Xc,
                     gradG, 0);
  hipLaunchKernelGGL(row_kernel, dim3(NN / 2), dim3(256), 0, stream, gradG,
                     tgt, lossG, gradG, 0);
  // half 2: sim rows 4096..8191, then row 4096..8191
  hipLaunchKernelGGL(sim_mfma_kernel, dim3(16 * 64), dim3(512), 0, stream, Xc,
                     gradG, 16);
  hipLaunchKernelGGL(row_kernel, dim3(NN / 2), dim3(256), 0, stream, gradG,
                     tgt, lossG, gradG, NN / 2);
}

// Round 16
// 179.479 us; speedup vs baseline: 1.1845x; 1.1845x over previous
//
#include <hip/hip_runtime.h>
#include <hip/hip_fp16.h>

#define NN 8192
#define DD 128

typedef _Float16 f16x8 __attribute__((ext_vector_type(8)));
typedef _Float16 f16x4 __attribute__((ext_vector_type(4)));
typedef float f32x4 __attribute__((ext_vector_type(4)));

// ---------------------------------------------------------------------------
// prep: Xc[row][0..127] = f16(x), Xc[row][128..255] = f16(x - f16(x)).
// sim = Xc @ Xc^T equals x@x^T up to ~1e-6.
// ---------------------------------------------------------------------------
__global__ __launch_bounds__(256) void prep_kernel(const float* __restrict__ X,
                                                   _Float16* __restrict__ Xc) {
  const int t = blockIdx.x * 256 + threadIdx.x;  // 8 elems per thread
  const size_t base = (size_t)t * 8;
  const int row = (int)(base >> 7);
  const int col = (int)(base & 127);
  float4 a = *(const float4*)&X[base];
  float4 b = *(const float4*)&X[base + 4];
  const float av[8] = {a.x, a.y, a.z, a.w, b.x, b.y, b.z, b.w};
  f16x8 h, l;
#pragma unroll
  for (int e = 0; e < 8; ++e) {
    const _Float16 hh = (_Float16)av[e];
    h[e] = hh;
    l[e] = (_Float16)(av[e] - (float)hh);
  }
  *(f16x8*)&Xc[(size_t)row * 256 + col] = h;
  *(f16x8*)&Xc[(size_t)row * 256 + 128 + col] = l;
}

// ---------------------------------------------------------------------------
// sim = Xc @ Xc^T  (R12 geometry — best measured; no spill), but sim is now
// stored as F16, IN-PLACE PER ROW: sim row i (8192 f16 = 16 KB) occupies the
// FIRST HALF of grad row i (32 KB). row_kernel block i reads exactly the
// region it later overwrites -> no cross-block hazard, dispatch-order-free.
// f16 rounding (<=2^-11) is safe vs the 0.0386 threshold: loss/grad
// derivative <= 2 -> 1e-3 value error; neg-boundary mask flips land where
// loss/grad ~ e^-30 ~ 0; pos-boundary is ~5 sigma out; diagonal rounds to
// exactly 1.0 -> excluded by s<1 (and hard-mining excludes near-1 positives
// in both ours and the reference anyway).
// Geometry: 256x128 tile, 512 thr (8 waves 4x2), wave tile 64x64 (acc[4][4]
// fits the 128-VGPR cap at 4 waves/EU). BK=32, 8 K-steps, double-buffered
// 24KB (A 16KB + B 8KB) = 48 KB LDS -> 2 blocks/CU.
// SYMMETRY ABANDONED (R2, R13). L3-scheduling games abandoned (R14, R15).
// DETERMINISM RULE (R9): plain __syncthreads() only.
// Schedule: STAGE(0); sync; { STAGE(ks+1); compute(ks); sync; }
// Swizzle: chunk ^= row&3 on BOTH global source (inverse) and ds_read.
// A/B fragments share the identical k-mapping -> k-permutation cancels.
// C/D layout (m89): col=lane&15, row=(lane>>4)*4+reg.
// Epilogue: TrH 64x136 f16 (17 KB union; 272B rows keep 16B-aligned b128
// reads), 4 phases of 64 rows, f16x8 stores (256B runs per tile row).
// Regular (non-NT) stores: simF16 lines get overwritten by row_kernel's grad
// stores before L3 eviction -> most never reach HBM.
// ---------------------------------------------------------------------------
__global__ __launch_bounds__(512, 4) void sim_mfma_kernel(
    const _Float16* __restrict__ Xc, char* __restrict__ simBytes) {
  __shared__ char smem[49152];  // buf b @ b*24576 (A 16KB, B 8KB); TrH unions

  // bijective XCD swizzle (2048 % 8 == 0)
  const int flat = blockIdx.x;
  const int swz = (flat & 7) * 256 + (flat >> 3);
  const int i0 = (swz >> 6) << 8;  // tile row (32 row-tiles of 256)
  const int j0 = (swz & 63) << 7;  // tile col (64 col-tiles of 128)

  const int tid = threadIdx.x;
  const int lane = tid & 63;
  const int w = tid >> 6;
  const int m = lane & 15, kq = lane >> 4;
  const int wr = w >> 1, wc = w & 1;  // wave rows wr*64+.., cols wc*64+..

  // Staging coords: 3 chunks of 16B per thread per K-step (A 16KB + B 8KB).
  int sg_off[3], sd_off[3], sg_row[3];
#pragma unroll
  for (int it = 0; it < 3; ++it) {
    const int C = it * 512 + tid;
    const int rq = C >> 2;          // row-quad index
    const int k4 = C & 3;
    const int k4p = k4 ^ (rq & 3);  // inverse swizzle on global source
    sg_row[it] = (C < 1024) ? (i0 + rq) : (j0 + rq - 256);
    sg_off[it] = k4p << 4;
    sd_off[it] = C * 16;
  }

#define STAGE(ks, b)                                                         \
  {                                                                          \
    _Pragma("unroll") for (int it = 0; it < 3; ++it) {                       \
      const char* g = (const char*)Xc + ((size_t)sg_row[it] << 9) +          \
                      (ks)*64 + sg_off[it];                                  \
      __builtin_amdgcn_global_load_lds(                                      \
          (const __attribute__((address_space(1))) void*)g,                  \
          (__attribute__((address_space(3))) void*)(smem + (b)*24576 +       \
                                                    sd_off[it]),             \
          16, 0, 0);                                                         \
    }                                                                        \
  }

  f32x4 acc[4][4] = {};

  STAGE(0, 0);
  __syncthreads();  // stage(0) landed (vmcnt 0 + barrier)

#pragma unroll
  for (int ks = 0; ks < 8; ++ks) {
    const int b = ks & 1;
    if (ks < 7) STAGE(ks + 1, b ^ 1);  // prefetch; drained at step-end sync
    const _Float16* As = (const _Float16*)(smem + b * 24576);
    const _Float16* Bs = (const _Float16*)(smem + b * 24576 + 16384);
    f16x8 af[4], bf[4];
#pragma unroll
    for (int f = 0; f < 4; ++f) {
      const int R = wr * 64 + f * 16 + m;  // R&3 == m&3
      af[f] = *(const f16x8*)(As + R * 32 + ((kq ^ (R & 3)) << 3));
    }
#pragma unroll
    for (int g = 0; g < 4; ++g) {
      const int R = wc * 64 + g * 16 + m;
      bf[g] = *(const f16x8*)(Bs + R * 32 + ((kq ^ (R & 3)) << 3));
    }
#pragma unroll
    for (int f = 0; f < 4; ++f)
#pragma unroll
      for (int g = 0; g < 4; ++g)
        acc[f][g] = __builtin_amdgcn_mfma_f32_16x16x32_f16(af[f], bf[g],
                                                           acc[f][g], 0, 0, 0);
    __syncthreads();  // drains vmcnt+lgkm; next-step buffer ready, WAR safe
  }
#undef STAGE

  // Epilogue: 4 phases of 64 rows through LDS as f16; TrH = 64 x 136 f16.
  _Float16* TrH = (_Float16*)smem;
#pragma unroll
  for (int ph = 0; ph < 4; ++ph) {
    if (ph) __syncthreads();
    if (wr == ph) {  // 2 waves (wc=0,1) own this 64-row band
#pragma unroll
      for (int f = 0; f < 4; ++f)
#pragma unroll
        for (int g = 0; g < 4; ++g)
#pragma unroll
          for (int rg = 0; rg < 4; ++rg)
            TrH[(f * 16 + kq * 4 + rg) * 136 + wc * 64 + g * 16 + m] =
                (_Float16)acc[f][g][rg];
    }
    __syncthreads();
#pragma unroll
    for (int it = 0; it < 2; ++it) {
      const int F = it * 512 + tid;   // [0,1024): 64 rows x 16 chunks
      const int row = F >> 4;
      const int c16 = F & 15;
      const f16x8 v = *(const f16x8*)&TrH[row * 136 + c16 * 8];
      char* dst = simBytes + (size_t)(i0 + ph * 64 + row) * 32768 +
                  (size_t)j0 * 2 + c16 * 16;
      *(f16x8*)dst = v;
    }
  }
}

// ---------------------------------------------------------------------------
// row_kernel: one block per row; sim row read as f16 from the first half of
// this block's own grad row (in-place), converted to f32 in registers.
// Native transcendentals, branchless epilogue, non-temporal output stores.
// ---------------------------------------------------------------------------
__global__ __launch_bounds__(256) void row_kernel(const char* simBytes,
                                                  const int* __restrict__ tgt,
                                                  float* lossG,
                                                  float* gradG) {
  __shared__ unsigned char tg[NN];
  __shared__ float redA[4];
  __shared__ float redB[4];
  const int i = blockIdx.x;
  const int tid = threadIdx.x;
  const size_t rowOff = (size_t)i * NN;

  for (int b = tid * 4; b < NN; b += 1024) {
    int4 t4 = *(const int4*)&tgt[b];
    tg[b + 0] = (unsigned char)t4.x;
    tg[b + 1] = (unsigned char)t4.y;
    tg[b + 2] = (unsigned char)t4.z;
    tg[b + 3] = (unsigned char)t4.w;
  }
  const unsigned char tci = (unsigned char)tgt[i];

  // Load this row's f16 sim (16 KB at the start of grad row i) -> f32 regs.
  float4 sv[8];
#pragma unroll
  for (int q = 0; q < 8; ++q) {
    const f16x4 h = *(const f16x4*)(simBytes + (size_t)i * 32768 +
                                    (size_t)(tid * 4 + q * 1024) * 2);
    sv[q] = make_float4((float)h[0], (float)h[1], (float)h[2], (float)h[3]);
  }
  __syncthreads();

  unsigned mmask = 0;
  float lmin = 1e30f, lmax = -1e30f;
#pragma unroll
  for (int q = 0; q < 8; ++q) {
    uchar4 t4 = *(const uchar4*)&tg[tid * 4 + q * 1024];
    const unsigned char tt[4] = {t4.x, t4.y, t4.z, t4.w};
    const float* sp = (const float*)&sv[q];
#pragma unroll
    for (int e = 0; e < 4; ++e) {
      const bool same = (tt[e] == tci);
      const float s = sp[e];
      if (same) {
        mmask |= (1u << (q * 4 + e));
        if (s < 1.0f) lmin = fminf(lmin, s);
      } else {
        lmax = fmaxf(lmax, s);
      }
    }
  }
#pragma unroll
  for (int off = 32; off > 0; off >>= 1) {
    lmin = fminf(lmin, __shfl_down(lmin, off));
    lmax = fmaxf(lmax, __shfl_down(lmax, off));
  }
  if ((tid & 63) == 0) {
    redA[tid >> 6] = lmin;
    redB[tid >> 6] = lmax;
  }
  __syncthreads();
  const float minpos = fminf(fminf(redA[0], redA[1]), fminf(redA[2], redA[3]));
  const float maxneg = fmaxf(fmaxf(redB[0], redB[1]), fmaxf(redB[2], redB[3]));
  __syncthreads();

  float pc = 0.f, nc = 0.f;
#pragma unroll
  for (int q = 0; q < 8; ++q) {
    const float* sp = (const float*)&sv[q];
#pragma unroll
    for (int e = 0; e < 4; ++e) {
      const bool same = (mmask >> (q * 4 + e)) & 1u;
      const float s = sp[e];
      if (same) {
        if (s < 1.0f && (s - 0.1f) < maxneg) pc += 1.f;
      } else {
        if ((s + 0.1f) > minpos) nc += 1.f;
      }
    }
  }
#pragma unroll
  for (int off = 32; off > 0; off >>= 1) {
    pc += __shfl_down(pc, off);
    nc += __shfl_down(nc, off);
  }
  if ((tid & 63) == 0) {
    redA[tid >> 6] = pc;
    redB[tid >> 6] = nc;
  }
  __syncthreads();
  const float pcnt = redA[0] + redA[1] + redA[2] + redA[3];
  const float ncnt = redB[0] + redB[1] + redB[2] + redB[3];
  const bool valid = (pcnt >= 1.f) && (ncnt >= 1.f);
  const float cp = -2.f / fmaxf(pcnt, 1.f);
  const float cn = 2.f / fmaxf(ncnt, 1.f);

#pragma unroll
  for (int q = 0; q < 8; ++q) {
    const float* sp = (const float*)&sv[q];
    float lo[4], go[4];
#pragma unroll
    for (int e = 0; e < 4; ++e) {
      const float s = sp[e];
      const bool same = (mmask >> (q * 4 + e)) & 1u;
      bool keep = same ? (s < 1.0f && (s - 0.1f) < maxneg)
                       : ((s + 0.1f) > minpos);
      keep = keep && valid;
      const float z = same ? fmaf(-2.f, s, 1.f) : fmaf(40.f, s, -20.f);
      const float ez = __expf(z);
      const float d = 1.f + ez;
      const float ll = __logf(d);
      const float sig = __fdividef(ez, d);
      const float lv = same ? ll : 0.05f * ll;
      const float gv = (same ? cp : cn) * sig;
      lo[e] = keep ? lv : 0.f;
      go[e] = keep ? gv : 0.f;
    }
    const size_t a = rowOff + (size_t)(tid * 4 + q * 1024);
    f32x4 lv4 = {lo[0], lo[1], lo[2], lo[3]};
    f32x4 gv4 = {go[0], go[1], go[2], go[3]};
    __builtin_nontemporal_store(lv4, (f32x4*)&lossG[a]);
    __builtin_nontemporal_store(gv4, (f32x4*)&gradG[a]);
  }
}

extern "C" void kernel_launch(void* const* d_in, const int* in_sizes, int n_in,
                              void* d_out, int out_size, void* d_ws,
                              size_t ws_size, hipStream_t stream) {
  const float* X = (const float*)d_in[0];
  const int* tgt = (const int*)d_in[1];
  float* out = (float*)d_out;
  float* lossG = out;                    // first N*N: pair_loss
  float* gradG = out + (size_t)NN * NN;  // second N*N: pair_grad
  char* simBytes = (char*)gradG;         // f16 sim row i @ grad row i start

  // Xc (4 MiB f16) lives at the start of lossG: read only by sim_mfma, and
  // row_kernel overwrites lossG strictly after sim is fully materialized.
  _Float16* Xc = (_Float16*)lossG;

  hipLaunchKernelGGL(prep_kernel, dim3(NN * DD / (256 * 8)), dim3(256), 0,
                     stream, X, Xc);
  hipLaunchKernelGGL(sim_mfma_kernel, dim3(32 * 64), dim3(512), 0, stream, Xc,
                     simBytes);
  hipLaunchKernelGGL(row_kernel, dim3(NN), dim3(256), 0, stream, simBytes,
                     tgt, lossG, gradG);
}